// Round 7
// baseline (182.376 us; speedup 1.0000x reference)
//
#include <hip/hip_runtime.h>

#define NUM_IDS 65
#define EDIM 32
#define NSUM (NUM_IDS * EDIM)      // 2080 per-label-dim sums
#define NTOT (NSUM + NUM_IDS)      // 2145 = sums + counts
#define LPAD 33                    // padded row for k3/k4 LDS tiles
#define ROWS 34                    // k1 row: 32 sums + count + pad; 136B keeps 8B align
#define COPYSZ 2212                // 65*34=2210 -> pad even for 8B-aligned copies
#define PIPE 6                     // k1 software-pipeline depth

// ws layout (float offsets)
#define WS_MEANS   0               // 2080
#define WS_COEF    2080            // 65
#define WS_SUMS    2145            // 2145 (2080 sums then 65 counts)
#define WS_PUSH    4290
#define WS_REG     4291
#define WS_CF      4292
#define WS_C       4293
#define WS_PULLACC 4294
#define WS_PART    4352            // per-block partials [nb1][NTOT]

__global__ void k0_zero(float* __restrict__ ws) {
    int i = blockIdx.x * 256 + threadIdx.x;
    if (i < NTOT) ws[WS_SUMS + i] = 0.f;
}

// Pass 1: wave-private non-atomic LDS segment reduction.
// 16 lanes per point (float2 each), 4 point-slots per wave.
// Depth-6 batched register pipeline hides HBM latency; intra-wave label
// collisions are merged in registers (canonical slot) — never serialized.
__global__ __launch_bounds__(256) void k1_reduce(const float2* __restrict__ emb2,
                                                 const int* __restrict__ lab,
                                                 float* __restrict__ ws,
                                                 int M, int nb1, int atomic_mode) {
    __shared__ float ls[4 * COPYSZ];   // 4 wave-private copies, 35.4 KB
    const int t = threadIdx.x;
    for (int j = t; j < 4 * COPYSZ; j += 256) ls[j] = 0.f;
    __syncthreads();

    const int wave = t >> 6;
    const int lane = t & 63;
    const int s = lane >> 4;           // point slot 0..3 within wave
    const int c = lane & 15;           // float2 chunk (dims 2c,2c+1)
    float* my = ls + wave * COPYSZ;

    const long stride = (long)nb1 * 16;            // 16 points per block-iter
    const long base   = (long)blockIdx.x * 16 + wave * 4;  // slot-0 point (wave-uniform)

    auto LOADIT = [&](int& dL, float2& dV, long pb) {
        long pp = pb + s;
        dL = 0; dV = make_float2(0.f, 0.f);
        if (pp < M) { dL = lab[pp]; dV = emb2[pp * 16 + c]; }
    };

    auto PROCESS = [&](int L, float2 v) {
        const bool act = (L > 0);
        int key = act ? L : (-1 - s);              // unique negatives never collide
        int k0 = __shfl(key, c);
        int k1 = __shfl(key, 16 + c);
        int k2 = __shfl(key, 32 + c);
        int k3 = __shfl(key, 48 + c);
        bool col = (k0 == k1) | (k0 == k2) | (k0 == k3) |
                   (k1 == k2) | (k1 == k3) | (k2 == k3);
        float sx = v.x, sy = v.y, cnt = 1.f;
        bool writer = act;
        if (col) {                                  // wave-uniform branch, ~9%
            int c1 = (k1 == k0) ? 0 : 1;
            int c2 = (k2 == k0) ? 0 : ((k2 == k1) ? 1 : 2);
            int c3 = (k3 == k0) ? 0 : ((k3 == k1) ? 1 : ((k3 == k2) ? 2 : 3));
            float x0 = __shfl(v.x, c),      y0 = __shfl(v.y, c);
            float x1 = __shfl(v.x, 16 + c), y1 = __shfl(v.y, 16 + c);
            float x2 = __shfl(v.x, 32 + c), y2 = __shfl(v.y, 32 + c);
            float x3 = __shfl(v.x, 48 + c), y3 = __shfl(v.y, 48 + c);
            sx = 0.f; sy = 0.f; cnt = 0.f;
            if (0 == s)  { sx += x0; sy += y0; cnt += 1.f; }
            if (c1 == s) { sx += x1; sy += y1; cnt += 1.f; }
            if (c2 == s) { sx += x2; sy += y2; cnt += 1.f; }
            if (c3 == s) { sx += x3; sy += y3; cnt += 1.f; }
            int cs = (s == 0) ? 0 : (s == 1) ? c1 : (s == 2) ? c2 : c3;
            writer = act && (cs == s);              // canonical slot writes merged sum
        }
        if (writer) {
            int off = L * ROWS + 2 * c;
            float2 o = *(float2*)(my + off);
            o.x += sx; o.y += sy;
            *(float2*)(my + off) = o;
            if (c == 0) my[L * ROWS + 32] += cnt;   // count
        }
    };

    int   LA[PIPE], LB[PIPE];
    float2 VA[PIPE], VB[PIPE];
    #pragma unroll
    for (int i = 0; i < PIPE; ++i) LOADIT(LA[i], VA[i], base + (long)i * stride);

    for (long pb = base; pb < M; pb += (long)PIPE * stride) {
        const long pn = pb + (long)PIPE * stride;
        #pragma unroll
        for (int i = 0; i < PIPE; ++i) LOADIT(LB[i], VB[i], pn + (long)i * stride);
        #pragma unroll
        for (int i = 0; i < PIPE; ++i) {
            if (pb + (long)i * stride < M) PROCESS(LA[i], VA[i]);  // uniform guard
        }
        #pragma unroll
        for (int i = 0; i < PIPE; ++i) { LA[i] = LB[i]; VA[i] = VB[i]; }
    }
    __syncthreads();

    // Flush: sum the 4 wave copies -> per-block partials (or global atomics).
    for (int j = t; j < NTOT; j += 256) {
        int off = (j < NSUM) ? ((j >> 5) * ROWS + (j & 31))
                             : ((j - NSUM) * ROWS + 32);
        float v = ls[off] + ls[COPYSZ + off] + ls[2 * COPYSZ + off] + ls[3 * COPYSZ + off];
        if (atomic_mode) {
            if (v != 0.f) atomicAdd(&ws[WS_SUMS + j], v);
        } else {
            ws[WS_PART + (size_t)blockIdx.x * NTOT + j] = v;
        }
    }
}

// Reduce per-block partials: each block handles 32 consecutive j (one 128B line
// per b-row), 8 b-lanes per j.
__global__ __launch_bounds__(256) void k2_reduce_partials(float* __restrict__ ws, int nb1) {
    const int t = threadIdx.x;
    const int jl = t & 31, bl = t >> 5;
    const int j = blockIdx.x * 32 + jl;
    const float* part = ws + WS_PART;
    float acc = 0.f;
    if (j < NTOT)
        for (int b = bl; b < nb1; b += 8) acc += part[(size_t)b * NTOT + j];
    __shared__ float red[256];
    red[t] = acc;
    __syncthreads();
    for (int sdown = 128; sdown >= 32; sdown >>= 1) {
        if (t < sdown) red[t] += red[t + sdown];
        __syncthreads();
    }
    if (t < 32) {
        int jj = blockIdx.x * 32 + t;
        if (jj < NTOT) ws[WS_SUMS + jj] = red[t];
    }
}

// Means, present mask, C, push loss, reg loss, coef; zero pull accumulator.
__global__ __launch_bounds__(256) void k3_finalize(float* __restrict__ ws) {
    __shared__ float lmean[NUM_IDS * LPAD];
    __shared__ float lcnt[NUM_IDS];
    __shared__ int   lpres[NUM_IDS];
    __shared__ float red[256];
    __shared__ float red2[256];
    const int t = threadIdx.x;
    const float* sg = ws + WS_SUMS;

    if (t < NUM_IDS) {
        float cv = sg[NSUM + t];
        lcnt[t] = cv;
        lpres[t] = (t > 0 && cv > 0.f) ? 1 : 0;
    }
    __syncthreads();

    for (int j = t; j < NSUM; j += 256) {
        int cc = j >> 5, e = j & 31;
        float m = sg[j] / fmaxf(lcnt[cc], 1.f);
        ws[WS_MEANS + j] = m;
        lmean[cc * LPAD + e] = m;
    }
    if (t < NUM_IDS) ws[WS_COEF + t] = lpres[t] ? (1.f / fmaxf(lcnt[t], 1.f)) : 0.f;
    __syncthreads();

    // Push: 65*64/2 = 2080 unordered pairs.
    float psum = 0.f;
    for (int pi = t; pi < 2080; pi += 256) {
        int i = 0, rem = pi;
        while (rem >= NUM_IDS - 1 - i) { rem -= NUM_IDS - 1 - i; ++i; }
        int jj = i + 1 + rem;
        if (lpres[i] && lpres[jj]) {
            float d2 = 0.f;
            #pragma unroll
            for (int e = 0; e < EDIM; ++e) {
                float d = lmean[i * LPAD + e] - lmean[jj * LPAD + e];
                d2 += d * d;
            }
            float pd = sqrtf(d2);
            float h = fmaxf(2.0f * 1.5f - pd, 0.f);  // 2*DELTA_PUSH = 3.0
            psum += h * h;
        }
    }
    // Reg: norm of present means.
    float rsum = 0.f;
    if (t < NUM_IDS && lpres[t]) {
        float m2 = 0.f;
        #pragma unroll
        for (int e = 0; e < EDIM; ++e) { float m = lmean[t * LPAD + e]; m2 += m * m; }
        rsum = sqrtf(m2);
    }
    red[t] = psum; red2[t] = rsum;
    __syncthreads();
    for (int sdown = 128; sdown > 0; sdown >>= 1) {
        if (t < sdown) { red[t] += red[t + sdown]; red2[t] += red2[t + sdown]; }
        __syncthreads();
    }
    if (t == 0) {
        int C = 0;
        for (int cc = 1; cc < NUM_IDS; ++cc) C += lpres[cc];
        float Cf = fmaxf((float)C, 1.f);
        long np = (long)C * (C - 1) / 2;
        ws[WS_PUSH] = (np > 0) ? red[0] / (float)np : 0.f;
        ws[WS_REG]  = red2[0] / Cf;
        ws[WS_CF]   = Cf;
        ws[WS_C]    = (float)C;
        ws[WS_PULLACC] = 0.f;
    }
}

// Pass 2: hinged pull distances; per-block scalar contribution.
__global__ __launch_bounds__(256) void k4_pull(const float4* __restrict__ emb4,
                                               const int* __restrict__ lab,
                                               float* __restrict__ ws,
                                               int M, int nb4) {
    __shared__ float lmean[NUM_IDS * LPAD];
    __shared__ float lcoef[NUM_IDS];
    __shared__ float lpull[NUM_IDS];
    __shared__ float red[NUM_IDS];
    const int t = threadIdx.x;
    for (int j = t; j < NSUM; j += 256) lmean[(j >> 5) * LPAD + (j & 31)] = ws[WS_MEANS + j];
    if (t < NUM_IDS) { lcoef[t] = ws[WS_COEF + t]; lpull[t] = 0.f; }
    __syncthreads();

    const int c = t & 7;
    const int stride = nb4 * 32;   // 256 threads / 8 = 32 points per block-iter
    for (int p = blockIdx.x * 32 + (t >> 3); p < M; p += stride) {
        int L = lab[p];
        float d2 = 0.f;
        if (L > 0) {
            float4 v = emb4[(size_t)p * 8 + c];
            int base = L * LPAD + c * 4;
            float dx = v.x - lmean[base + 0];
            float dy = v.y - lmean[base + 1];
            float dz = v.z - lmean[base + 2];
            float dw = v.w - lmean[base + 3];
            d2 = dx * dx + dy * dy + dz * dz + dw * dw;
        }
        d2 += __shfl_xor(d2, 1);
        d2 += __shfl_xor(d2, 2);
        d2 += __shfl_xor(d2, 4);
        if (c == 0 && L > 0 && d2 > 0.f) {
            float dist = sqrtf(d2);
            float h = fmaxf(dist - 0.5f, 0.f);   // DELTA_PULL = 0.5
            atomicAdd(&lpull[L], h * h);
        }
    }
    __syncthreads();
    if (t < NUM_IDS) red[t] = lpull[t] * lcoef[t];
    __syncthreads();
    if (t == 0) {
        float sacc = 0.f;
        for (int cc = 1; cc < NUM_IDS; ++cc) sacc += red[cc];
        atomicAdd(&ws[WS_PULLACC], sacc);
    }
}

__global__ void k5_final(const float* __restrict__ ws, float* __restrict__ out) {
    if (threadIdx.x == 0) {
        float C = ws[WS_C];
        float total = 0.f;
        if (C > 0.f) {
            total = ws[WS_PULLACC] / ws[WS_CF]   // ALPHA = 1
                  + ws[WS_PUSH]                  // BETA = 1
                  + 0.001f * ws[WS_REG];         // GAMMA = 0.001
        }
        out[0] = total;
    }
}

extern "C" void kernel_launch(void* const* d_in, const int* in_sizes, int n_in,
                              void* d_out, int out_size, void* d_ws, size_t ws_size,
                              hipStream_t stream) {
    const float2* emb2 = (const float2*)d_in[0];
    const float4* emb4 = (const float4*)d_in[0];
    const int* lab = (const int*)d_in[1];
    float* ws = (float*)d_ws;
    float* out = (float*)d_out;
    const int M = in_sizes[1];

    // Size pass-1 grid to available workspace; fall back to global atomics if tiny.
    long ws_floats = (long)(ws_size / 4);
    long avail = ws_floats - WS_PART - 64;
    int nb1 = (int)(avail / NTOT);
    if (nb1 > 1024) nb1 = 1024;
    int atomic_mode = (nb1 < 8) ? 1 : 0;
    if (atomic_mode) {
        nb1 = 1024;
        k0_zero<<<dim3(9), dim3(256), 0, stream>>>(ws);
    }

    k1_reduce<<<dim3(nb1), dim3(256), 0, stream>>>(emb2, lab, ws, M, nb1, atomic_mode);
    if (!atomic_mode)
        k2_reduce_partials<<<dim3((NTOT + 31) / 32), dim3(256), 0, stream>>>(ws, nb1);
    k3_finalize<<<dim3(1), dim3(256), 0, stream>>>(ws);
    const int nb4 = 2048;
    k4_pull<<<dim3(nb4), dim3(256), 0, stream>>>(emb4, lab, ws, M, nb4);
    k5_final<<<dim3(1), dim3(64), 0, stream>>>(ws, out);
}

// Round 8
// 179.025 us; speedup vs baseline: 1.0187x; 1.0187x over previous
//
#include <hip/hip_runtime.h>

#define NUM_IDS 65
#define EDIM 32
#define NSUM (NUM_IDS * EDIM)      // 2080 per-label-dim sums
#define NTOT (NSUM + NUM_IDS)      // 2145 = sums + counts
#define LPAD 33                    // padded row for k3/k4 LDS tiles
#define ROWS 34                    // k1 row: 32 sums + count + pad; 136B keeps 8B align
#define COPYSZ 2212                // 65*34=2210 -> pad even for 8B-aligned copies

// ws layout (float offsets)
#define WS_MEANS   0               // 2080
#define WS_COEF    2080            // 65
#define WS_SUMS    2145            // 2145 (2080 sums then 65 counts)
#define WS_PUSH    4290
#define WS_REG     4291
#define WS_CF      4292
#define WS_C       4293
#define WS_PULLACC 4294
#define WS_PART    4352            // per-block partials [nb1][NTOT]

__global__ void k0_zero(float* __restrict__ ws) {
    int i = blockIdx.x * 256 + threadIdx.x;
    if (i < NTOT) ws[WS_SUMS + i] = 0.f;
}

// Pass 1: wave-private non-atomic LDS segment reduction.
// 16 lanes per point (float2 each), 4 point-slots per wave.
// Ping-pong software pipeline with NAMED registers (no arrays, no rotates):
// ~8 global loads stay in flight per wave at all times.
__global__ __launch_bounds__(256) void k1_reduce(const float2* __restrict__ emb2,
                                                 const int* __restrict__ lab,
                                                 float* __restrict__ ws,
                                                 int M, int nb1, int atomic_mode) {
    __shared__ float ls[4 * COPYSZ];   // 4 wave-private copies, 35.4 KB
    const int t = threadIdx.x;
    for (int j = t; j < 4 * COPYSZ; j += 256) ls[j] = 0.f;
    __syncthreads();

    const int wave = t >> 6;
    const int lane = t & 63;
    const int s = lane >> 4;           // point slot 0..3 within wave
    const int c = lane & 15;           // float2 chunk (dims 2c,2c+1)
    float* my = ls + wave * COPYSZ;

    const long stride = (long)nb1 * 16;                    // 16 points per block-iter
    const long base   = (long)blockIdx.x * 16 + wave * 4;  // wave-uniform

    auto LD = [&](long q, int& L, float2& v) {
        long pp = q + s;
        if (pp < M) { L = lab[pp]; v = emb2[pp * 16 + c]; }
        else        { L = 0; v = make_float2(0.f, 0.f); }
    };

    auto PR = [&](int L, float2 v) {
        const bool act = (L > 0);
        int key = act ? L : (-1 - s);              // unique negatives never collide
        int k0 = __shfl(key, c);
        int k1 = __shfl(key, 16 + c);
        int k2 = __shfl(key, 32 + c);
        int k3 = __shfl(key, 48 + c);
        bool col = (k0 == k1) | (k0 == k2) | (k0 == k3) |
                   (k1 == k2) | (k1 == k3) | (k2 == k3);
        float sx = v.x, sy = v.y, cnt = 1.f;
        bool writer = act;
        if (col) {                                  // wave-uniform branch, ~9%
            int c1 = (k1 == k0) ? 0 : 1;
            int c2 = (k2 == k0) ? 0 : ((k2 == k1) ? 1 : 2);
            int c3 = (k3 == k0) ? 0 : ((k3 == k1) ? 1 : ((k3 == k2) ? 2 : 3));
            float x0 = __shfl(v.x, c),      y0 = __shfl(v.y, c);
            float x1 = __shfl(v.x, 16 + c), y1 = __shfl(v.y, 16 + c);
            float x2 = __shfl(v.x, 32 + c), y2 = __shfl(v.y, 32 + c);
            float x3 = __shfl(v.x, 48 + c), y3 = __shfl(v.y, 48 + c);
            sx = 0.f; sy = 0.f; cnt = 0.f;
            if (0 == s)  { sx += x0; sy += y0; cnt += 1.f; }
            if (c1 == s) { sx += x1; sy += y1; cnt += 1.f; }
            if (c2 == s) { sx += x2; sy += y2; cnt += 1.f; }
            if (c3 == s) { sx += x3; sy += y3; cnt += 1.f; }
            int cs = (s == 0) ? 0 : (s == 1) ? c1 : (s == 2) ? c2 : c3;
            writer = act && (cs == s);              // canonical slot writes merged sum
        }
        if (writer) {
            int off = L * ROWS + 2 * c;
            float2 o = *(float2*)(my + off);
            o.x += sx; o.y += sy;
            *(float2*)(my + off) = o;
            if (c == 0) my[L * ROWS + 32] += cnt;   // count
        }
    };

    int    La0, La1, La2, La3, Lb0, Lb1, Lb2, Lb3;
    float2 va0, va1, va2, va3, vb0, vb1, vb2, vb3;

    long pA = base;
    LD(pA,              La0, va0);
    LD(pA +     stride, La1, va1);
    LD(pA + 2 * stride, La2, va2);
    LD(pA + 3 * stride, La3, va3);

    while (pA < M) {
        const long pB = pA + 4 * stride;
        LD(pB,              Lb0, vb0);
        LD(pB +     stride, Lb1, vb1);
        LD(pB + 2 * stride, Lb2, vb2);
        LD(pB + 3 * stride, Lb3, vb3);
        PR(La0, va0); PR(La1, va1); PR(La2, va2); PR(La3, va3);

        const long pA2 = pB + 4 * stride;
        LD(pA2,              La0, va0);
        LD(pA2 +     stride, La1, va1);
        LD(pA2 + 2 * stride, La2, va2);
        LD(pA2 + 3 * stride, La3, va3);
        PR(Lb0, vb0); PR(Lb1, vb1); PR(Lb2, vb2); PR(Lb3, vb3);

        pA = pA2;
    }
    __syncthreads();

    // Flush: sum the 4 wave copies -> per-block partials (or global atomics).
    for (int j = t; j < NTOT; j += 256) {
        int off = (j < NSUM) ? ((j >> 5) * ROWS + (j & 31))
                             : ((j - NSUM) * ROWS + 32);
        float v = ls[off] + ls[COPYSZ + off] + ls[2 * COPYSZ + off] + ls[3 * COPYSZ + off];
        if (atomic_mode) {
            if (v != 0.f) atomicAdd(&ws[WS_SUMS + j], v);
        } else {
            ws[WS_PART + (size_t)blockIdx.x * NTOT + j] = v;
        }
    }
}

// Reduce per-block partials: each block handles 32 consecutive j (one 128B line
// per b-row), 8 b-lanes per j.
__global__ __launch_bounds__(256) void k2_reduce_partials(float* __restrict__ ws, int nb1) {
    const int t = threadIdx.x;
    const int jl = t & 31, bl = t >> 5;
    const int j = blockIdx.x * 32 + jl;
    const float* part = ws + WS_PART;
    float acc = 0.f;
    if (j < NTOT)
        for (int b = bl; b < nb1; b += 8) acc += part[(size_t)b * NTOT + j];
    __shared__ float red[256];
    red[t] = acc;
    __syncthreads();
    for (int sdown = 128; sdown >= 32; sdown >>= 1) {
        if (t < sdown) red[t] += red[t + sdown];
        __syncthreads();
    }
    if (t < 32) {
        int jj = blockIdx.x * 32 + t;
        if (jj < NTOT) ws[WS_SUMS + jj] = red[t];
    }
}

// Means, present mask, C, push loss, reg loss, coef; zero pull accumulator.
__global__ __launch_bounds__(256) void k3_finalize(float* __restrict__ ws) {
    __shared__ float lmean[NUM_IDS * LPAD];
    __shared__ float lcnt[NUM_IDS];
    __shared__ int   lpres[NUM_IDS];
    __shared__ float red[256];
    __shared__ float red2[256];
    const int t = threadIdx.x;
    const float* sg = ws + WS_SUMS;

    if (t < NUM_IDS) {
        float cv = sg[NSUM + t];
        lcnt[t] = cv;
        lpres[t] = (t > 0 && cv > 0.f) ? 1 : 0;
    }
    __syncthreads();

    for (int j = t; j < NSUM; j += 256) {
        int cc = j >> 5, e = j & 31;
        float m = sg[j] / fmaxf(lcnt[cc], 1.f);
        ws[WS_MEANS + j] = m;
        lmean[cc * LPAD + e] = m;
    }
    if (t < NUM_IDS) ws[WS_COEF + t] = lpres[t] ? (1.f / fmaxf(lcnt[t], 1.f)) : 0.f;
    __syncthreads();

    // Push: 65*64/2 = 2080 unordered pairs.
    float psum = 0.f;
    for (int pi = t; pi < 2080; pi += 256) {
        int i = 0, rem = pi;
        while (rem >= NUM_IDS - 1 - i) { rem -= NUM_IDS - 1 - i; ++i; }
        int jj = i + 1 + rem;
        if (lpres[i] && lpres[jj]) {
            float d2 = 0.f;
            #pragma unroll
            for (int e = 0; e < EDIM; ++e) {
                float d = lmean[i * LPAD + e] - lmean[jj * LPAD + e];
                d2 += d * d;
            }
            float pd = sqrtf(d2);
            float h = fmaxf(2.0f * 1.5f - pd, 0.f);  // 2*DELTA_PUSH = 3.0
            psum += h * h;
        }
    }
    // Reg: norm of present means.
    float rsum = 0.f;
    if (t < NUM_IDS && lpres[t]) {
        float m2 = 0.f;
        #pragma unroll
        for (int e = 0; e < EDIM; ++e) { float m = lmean[t * LPAD + e]; m2 += m * m; }
        rsum = sqrtf(m2);
    }
    red[t] = psum; red2[t] = rsum;
    __syncthreads();
    for (int sdown = 128; sdown > 0; sdown >>= 1) {
        if (t < sdown) { red[t] += red[t + sdown]; red2[t] += red2[t + sdown]; }
        __syncthreads();
    }
    if (t == 0) {
        int C = 0;
        for (int cc = 1; cc < NUM_IDS; ++cc) C += lpres[cc];
        float Cf = fmaxf((float)C, 1.f);
        long np = (long)C * (C - 1) / 2;
        ws[WS_PUSH] = (np > 0) ? red[0] / (float)np : 0.f;
        ws[WS_REG]  = red2[0] / Cf;
        ws[WS_CF]   = Cf;
        ws[WS_C]    = (float)C;
        ws[WS_PULLACC] = 0.f;
    }
}

// Pass 2: hinged pull distances; ping-pong pipelined loads.
__global__ __launch_bounds__(256) void k4_pull(const float4* __restrict__ emb4,
                                               const int* __restrict__ lab,
                                               float* __restrict__ ws,
                                               int M, int nb4) {
    __shared__ float lmean[NUM_IDS * LPAD];
    __shared__ float lcoef[NUM_IDS];
    __shared__ float lpull[NUM_IDS];
    __shared__ float red[NUM_IDS];
    const int t = threadIdx.x;
    for (int j = t; j < NSUM; j += 256) lmean[(j >> 5) * LPAD + (j & 31)] = ws[WS_MEANS + j];
    if (t < NUM_IDS) { lcoef[t] = ws[WS_COEF + t]; lpull[t] = 0.f; }
    __syncthreads();

    const int c = t & 7;
    const long stride = (long)nb4 * 32;   // 32 points per block-iter
    const long start = (long)blockIdx.x * 32 + (t >> 3);

    auto LD = [&](long p, int& L, float4& v) {
        if (p < M) { L = lab[p]; v = emb4[p * 8 + c]; }
        else       { L = 0; v = make_float4(0.f, 0.f, 0.f, 0.f); }
    };
    auto PR = [&](int L, float4 v) {
        float d2 = 0.f;
        if (L > 0) {
            int bse = L * LPAD + c * 4;
            float dx = v.x - lmean[bse + 0];
            float dy = v.y - lmean[bse + 1];
            float dz = v.z - lmean[bse + 2];
            float dw = v.w - lmean[bse + 3];
            d2 = dx * dx + dy * dy + dz * dz + dw * dw;
        }
        d2 += __shfl_xor(d2, 1);
        d2 += __shfl_xor(d2, 2);
        d2 += __shfl_xor(d2, 4);
        if (c == 0 && L > 0 && d2 > 0.f) {
            float dist = sqrtf(d2);
            float h = fmaxf(dist - 0.5f, 0.f);   // DELTA_PULL = 0.5
            atomicAdd(&lpull[L], h * h);
        }
    };

    int L0, L1;
    float4 v0, v1;
    long pA = start;
    LD(pA, L0, v0);
    while (pA < M) {
        const long pB = pA + stride;
        LD(pB, L1, v1);
        PR(L0, v0);
        const long pA2 = pB + stride;
        LD(pA2, L0, v0);
        PR(L1, v1);
        pA = pA2;
    }
    __syncthreads();
    if (t < NUM_IDS) red[t] = lpull[t] * lcoef[t];
    __syncthreads();
    if (t == 0) {
        float sacc = 0.f;
        for (int cc = 1; cc < NUM_IDS; ++cc) sacc += red[cc];
        atomicAdd(&ws[WS_PULLACC], sacc);
    }
}

__global__ void k5_final(const float* __restrict__ ws, float* __restrict__ out) {
    if (threadIdx.x == 0) {
        float C = ws[WS_C];
        float total = 0.f;
        if (C > 0.f) {
            total = ws[WS_PULLACC] / ws[WS_CF]   // ALPHA = 1
                  + ws[WS_PUSH]                  // BETA = 1
                  + 0.001f * ws[WS_REG];         // GAMMA = 0.001
        }
        out[0] = total;
    }
}

extern "C" void kernel_launch(void* const* d_in, const int* in_sizes, int n_in,
                              void* d_out, int out_size, void* d_ws, size_t ws_size,
                              hipStream_t stream) {
    const float2* emb2 = (const float2*)d_in[0];
    const float4* emb4 = (const float4*)d_in[0];
    const int* lab = (const int*)d_in[1];
    float* ws = (float*)d_ws;
    float* out = (float*)d_out;
    const int M = in_sizes[1];

    // Size pass-1 grid to available workspace; fall back to global atomics if tiny.
    long ws_floats = (long)(ws_size / 4);
    long avail = ws_floats - WS_PART - 64;
    int nb1 = (int)(avail / NTOT);
    if (nb1 > 1024) nb1 = 1024;
    int atomic_mode = (nb1 < 8) ? 1 : 0;
    if (atomic_mode) {
        nb1 = 1024;
        k0_zero<<<dim3(9), dim3(256), 0, stream>>>(ws);
    }

    k1_reduce<<<dim3(nb1), dim3(256), 0, stream>>>(emb2, lab, ws, M, nb1, atomic_mode);
    if (!atomic_mode)
        k2_reduce_partials<<<dim3((NTOT + 31) / 32), dim3(256), 0, stream>>>(ws, nb1);
    k3_finalize<<<dim3(1), dim3(256), 0, stream>>>(ws);
    const int nb4 = 2048;
    k4_pull<<<dim3(nb4), dim3(256), 0, stream>>>(emb4, lab, ws, M, nb4);
    k5_final<<<dim3(1), dim3(64), 0, stream>>>(ws, out);
}